// Round 7
// baseline (312.524 us; speedup 1.0000x reference)
//
#include <hip/hip_runtime.h>

#define B_   8
#define C_   128
#define H_   128
#define W_   128
#define HW_  16384

typedef short v8s __attribute__((ext_vector_type(8)));
typedef float v4f __attribute__((ext_vector_type(4)));

// LDS B-tile row: 130 px-slots x 32B (16ch bf16). Row stride 4160 B.
#define ROWB 4160

__device__ __forceinline__ float bf2f(unsigned short u) {
  unsigned int v = ((unsigned int)u) << 16;
  float f; __builtin_memcpy(&f, &v, 4); return f;
}
__device__ __forceinline__ unsigned short f2us(float f) {
  unsigned int u; __builtin_memcpy(&u, &f, 4);
  u += 0x7fffu + ((u >> 16) & 1u);           // RNE
  return (unsigned short)(u >> 16);
}

// ---- prep: transpose_x + both weight packs + zero scratch, one launch -------
// blocks [0,4096): transpose x fp32 [b][c][i][j] -> bf16 [b][cg][i][j][16c]
// blocks [4096,5376): pack w_off (G=16); [5376,6016): pack w_conv (G=8)
__global__ __launch_bounds__(256) void prep(const float* __restrict__ x,
                                            unsigned short* __restrict__ xt,
                                            const float* __restrict__ w_off,
                                            const float* __restrict__ w_conv,
                                            unsigned short* __restrict__ pack_off,
                                            unsigned short* __restrict__ pack_main,
                                            uint4* __restrict__ zb) {
  __shared__ alignas(16) unsigned short t[32 * 132];
  const int bid = blockIdx.x, tid = threadIdx.x;
  if (bid < 4096) {
    const int j0 = (bid & 3) * 32, i = (bid >> 2) & 127, b = bid >> 9;
    for (int e = tid; e < 1024; e += 256) {        // float4: 16B/lane, coalesced
      int c = e >> 3, j4 = (e & 7) << 2;
      float4 v = *(const float4*)&x[((b * C_ + c) * H_ + i) * W_ + j0 + j4];
      t[(j4 + 0) * 132 + c] = f2us(v.x);
      t[(j4 + 1) * 132 + c] = f2us(v.y);
      t[(j4 + 2) * 132 + c] = f2us(v.z);
      t[(j4 + 3) * 132 + c] = f2us(v.w);
    }
    __syncthreads();
    for (int f = tid; f < 1024; f += 256) {        // coalesced: 4 thr = 32B of one px
      int cg = f >> 7, g = f & 127;
      int j = g >> 2, c4 = (g & 3) << 2;
      uint2 v = *(const uint2*)&t[j * 132 + cg * 16 + c4];
      *(uint2*)(xt + ((size_t)(b * 8 + cg) * HW_ + i * W_ + j0 + j) * 16 + c4) = v;
    }
    return;
  }
  const int pb = bid - 4096;
  if (pb == 0) zb[tid] = (uint4){0u, 0u, 0u, 0u};  // 4 KB zeros
  const float* w;
  unsigned short* pack;
  int G, idx;
  if (pb < 1280) { w = w_off;  pack = pack_off;  G = 16; idx = pb * 256 + tid; }
  else           { w = w_conv; pack = pack_main; G = 8;  idx = (pb - 1280) * 256 + tid; }
  if (idx >= 20480 * G) return;
  int j  = idx & 7;
  int l  = (idx >> 3) & 63;
  int g  = (idx >> 9) % G;
  int t2 = idx / (512 * G);
  int pp = t2 % 5;
  int cc = t2 / 5;
  int oc = g * 16 + (l & 15);
  int kk = ((l >> 4) << 3) + j;
  int ic = (cc << 4) + (kk & 15);
  int rs = pp * 2 + (kk >> 4);
  float v = (rs < 9) ? w[(oc * C_ + ic) * 9 + rs] : 0.f;
  pack[idx] = f2us(v);
}

// ---------------- implicit-GEMM conv via MFMA, global_load_lds staging -------
// 8-wave / 2-output-row geometry with the PROVEN R3 inner loop (no A-dbuf; it
// is what spilled R2 past 128 regs). 64 VGPR + 64 AGPR = 128 -> with
// launch_bounds(512,4): 2 blocks/CU = 16 waves/CU (same wave count as R3's
// 4x4) but staging instrs -33% and barriers -50% per unit output.
// Per cc: barrier -> 16x1KB DMA (4 halo rows) -> barrier -> 5 pp MFMA phases.
// MODE 0: plain bf16 store (offset conv). MODE 1: +bias+relu+BN partials.
template <int MODE, int G>
__global__ __launch_bounds__(512, 4) void conv_gemm(const unsigned short* __restrict__ xt,
                                                    const unsigned short* __restrict__ pack,
                                                    const float* __restrict__ bias,
                                                    const char* __restrict__ zb,
                                                    unsigned short* __restrict__ outp,
                                                    float* __restrict__ ps) {
  __shared__ alignas(16) char rawb[4 * ROWB];      // 16640 B
  __shared__ float bs1[128], bs2[128];

  const int nb = blockIdx.x;
  int b, ip, mt;
  {
    int xcd = nb & 7, r = nb >> 3;
    if (MODE == 0) { b = r >> 4; mt = (r >> 3) & 1; ip = xcd * 8 + (r & 7); }
    else           { b = r >> 3; mt = 0;            ip = xcd * 8 + (r & 7); }
  }
  const int i0 = ip * 2;                           // output rows i0, i0+1
  const int tid  = threadIdx.x;
  const int lane = tid & 63, wid = tid >> 6;       // wid 0..7
  const int q = lane >> 4, n = lane & 15;
  const int wr = wid & 1, wm = (wid >> 1) & 1, wn = wid >> 2;  // wn 0..1

  if (MODE == 1 && tid < 128) { bs1[tid] = 0.f; bs2[tid] = 0.f; }
  // halo-edge slots (px -1 / 128) of the 4 staged rows are always zero
  if (tid < 16) {
    int r = tid >> 2, rem = tid & 3, side = rem >> 1, h = rem & 1;
    *(uint4*)(rawb + r * ROWB + (side ? 129 * 32 : 0) + h * 16) = (uint4){0u,0u,0u,0u};
  }

  // per-pp LDS base: rs -> (staged row wr+dr, col s), 32B px stride,
  // (q&1) picks 16B half
  int boff[5];
#pragma unroll
  for (int pp = 0; pp < 5; ++pp) {
    int rs = pp * 2 + (q >> 1);
    if (rs > 8) rs = 8;                            // pad half: A is zero there
    int dr = (rs >= 6) ? 2 : ((rs >= 3) ? 1 : 0);
    int s = rs - dr * 3;
    boff[pp] = (wr + dr) * ROWB + s * 32 + (q & 1) * 16;
  }
  const int pcol = (wn * 64 + n) * 32;

  v4f acc[4][4];
#pragma unroll
  for (int a = 0; a < 4; ++a)
#pragma unroll
    for (int c = 0; c < 4; ++c) acc[a][c] = (v4f){0.f, 0.f, 0.f, 0.f};

  const v8s* packv = (const v8s*)pack;
  const int gbase = mt * 8 + wm * 4;

  for (int cc = 0; cc < 8; ++cc) {
    __syncthreads();                               // prev compute done
    // stage 4 halo rows (16 x 1KB chunks; wave w -> chunks 2w, 2w+1)
    const char* ccbase = (const char*)xt + (size_t)(b * 8 + cc) * (HW_ * 32);
#pragma unroll
    for (int t = 0; t < 2; ++t) {
      int c = wid * 2 + t, r = c >> 2, k = c & 3;
      int ii = i0 + r - 1;
      const char* src = ((unsigned)ii < 128u)
                          ? ccbase + ii * 4096 + k * 1024 + lane * 16
                          : zb + lane * 16;
      __builtin_amdgcn_global_load_lds(
          (const __attribute__((address_space(1))) unsigned int*)src,
          (__attribute__((address_space(3))) unsigned int*)(rawb + r * ROWB + 32 + k * 1024),
          16, 0, 0);
    }
    __syncthreads();                               // vmcnt drain: DMA visible

#pragma unroll
    for (int pp = 0; pp < 5; ++pp) {
      const v8s* ap = packv + ((cc * 5 + pp) * G + gbase) * 64 + lane;
      v8s Af[4];
#pragma unroll
      for (int fm = 0; fm < 4; ++fm) Af[fm] = ap[fm * 64];
      v8s Bf[4];
#pragma unroll
      for (int fn = 0; fn < 4; ++fn)
        Bf[fn] = *(const v8s*)(rawb + boff[pp] + pcol + fn * 512);
#pragma unroll
      for (int fm = 0; fm < 4; ++fm) {
#pragma unroll
        for (int fn = 0; fn < 4; ++fn)
          acc[fm][fn] = __builtin_amdgcn_mfma_f32_16x16x32_bf16(Af[fm], Bf[fn],
                                                                acc[fm][fn], 0, 0, 0);
      }
    }
  }

  const int OC = G * 16;
  const int ob = (b * OC + mt * 128 + wm * 64) * HW_ + (i0 + wr) * W_ + wn * 64;

  if (MODE == 0) {
#pragma unroll
    for (int fm = 0; fm < 4; ++fm)
#pragma unroll
      for (int fn = 0; fn < 4; ++fn)
#pragma unroll
        for (int rr = 0; rr < 4; ++rr)
          outp[ob + (fm * 16 + q * 4 + rr) * HW_ + fn * 16 + n] = f2us(acc[fm][fn][rr]);
  } else {
    float bv[4][4], s1a[4][4], s2a[4][4];
#pragma unroll
    for (int fm = 0; fm < 4; ++fm)
#pragma unroll
      for (int rr = 0; rr < 4; ++rr) {
        bv[fm][rr] = bias[wm * 64 + fm * 16 + q * 4 + rr];
        s1a[fm][rr] = 0.f; s2a[fm][rr] = 0.f;
      }
#pragma unroll
    for (int fm = 0; fm < 4; ++fm)
#pragma unroll
      for (int fn = 0; fn < 4; ++fn)
#pragma unroll
        for (int rr = 0; rr < 4; ++rr) {
          float v = acc[fm][fn][rr] + bv[fm][rr];
          v = fmaxf(v, 0.f);
          outp[ob + (fm * 16 + q * 4 + rr) * HW_ + fn * 16 + n] = f2us(v);
          s1a[fm][rr] += v; s2a[fm][rr] += v * v;
        }
#pragma unroll
    for (int fm = 0; fm < 4; ++fm)
#pragma unroll
      for (int rr = 0; rr < 4; ++rr) {
        float s1 = s1a[fm][rr], s2 = s2a[fm][rr];
#pragma unroll
        for (int m = 1; m < 16; m <<= 1) {
          s1 += __shfl_xor(s1, m);
          s2 += __shfl_xor(s2, m);
        }
        if (n == 0) {
          atomicAdd(&bs1[wm * 64 + fm * 16 + q * 4 + rr], s1);
          atomicAdd(&bs2[wm * 64 + fm * 16 + q * 4 + rr], s2);
        }
      }
    __syncthreads();
    if (tid < 128) {
      ps[nb * 128 + tid]          = bs1[tid];
      ps[131072 + nb * 128 + tid] = bs2[tid];
    }
  }
}

// ------- deform + fused transpose to [b][cg][i][j][16c] ----------------------
__global__ __launch_bounds__(256) void deform_t(const float* __restrict__ x,
                                                const unsigned short* __restrict__ offs,
                                                unsigned short* __restrict__ xofft) {
  __shared__ alignas(16) unsigned short t[64 * 132];
  const int jh = blockIdx.x & 1, i = blockIdx.x >> 1, b = blockIdx.y;
  const int j0 = jh * 64;
  const int tid = threadIdx.x;
  for (int e = tid; e < 4096; e += 256) {          // pair index: c = e>>5, pr = e&31
    int c = e >> 5, pr = e & 31;
    int j = j0 + pr * 2;
    int qpix = (i << 7) + j;
    int oidx = (b << 22) + (c << 15) + 2 * qpix;   // quirky reshape semantics
    uint2 two = *(const uint2*)(offs + oidx);      // 8B: offsets for px j, j+1
    const float* img = x + ((b * C_ + c) << 14);
#pragma unroll
    for (int u = 0; u < 2; ++u) {
      unsigned int p = (u == 0) ? two.x : two.y;
      float oy = bf2f((unsigned short)(p & 0xffffu));
      float ox = bf2f((unsigned short)(p >> 16));
      float yc = fminf(fmaxf(oy + (float)i, 0.f), 127.f);
      float xc = fminf(fmaxf(ox + (float)(j + u), 0.f), 127.f);
      float y0f = floorf(yc), y1f = ceilf(yc);
      float x0f = floorf(xc), x1f = ceilf(xc);
      int y0 = (int)y0f, y1 = (int)y1f, x0 = (int)x0f, x1 = (int)x1f;
      float v_lt = img[y0 * W_ + x0];
      float v_rb = img[y1 * W_ + x1];
      float v_lb = img[y0 * W_ + x1];
      float v_rt = img[y1 * W_ + x0];
      float dy = yc - y0f, dx = xc - x0f;
      float v_t = v_lt + (v_rt - v_lt) * dy;
      float v_b = v_lb + (v_rb - v_lb) * dy;
      float o   = v_t + (v_b - v_t) * dx;
      t[(pr * 2 + u) * 132 + c] = f2us(o);
    }
  }
  __syncthreads();
  for (int f = tid; f < 2048; f += 256) {          // coalesced: 4 thr = 32B of one px
    int cg = f >> 8, g = f & 255;
    int jj = g >> 2, c4 = (g & 3) << 2;
    uint2 v = *(const uint2*)&t[jj * 132 + cg * 16 + c4];
    *(uint2*)(xofft + ((size_t)(b * 8 + cg) * HW_ + i * W_ + j0 + jj) * 16 + c4) = v;
  }
}

// ---------------- BN finalize: fold stats into scale/shift -------------------
__global__ __launch_bounds__(256) void bn_finalize(const float* __restrict__ ps,
                                                   const float* __restrict__ gamma,
                                                   const float* __restrict__ beta,
                                                   float* __restrict__ stats) {
  const int c = blockIdx.x, tid = threadIdx.x;
  float s1 = 0.f, s2 = 0.f;
  for (int k = tid; k < 512; k += 256) {
    s1 += ps[k * 128 + c];
    s2 += ps[131072 + k * 128 + c];
  }
#pragma unroll
  for (int m = 32; m > 0; m >>= 1) {
    s1 += __shfl_down(s1, m);
    s2 += __shfl_down(s2, m);
  }
  __shared__ float l1[4], l2[4];
  int wid = tid >> 6;
  if ((tid & 63) == 0) { l1[wid] = s1; l2[wid] = s2; }
  __syncthreads();
  if (tid == 0) {
    s1 = l1[0] + l1[1] + l1[2] + l1[3];
    s2 = l2[0] + l2[1] + l2[2] + l2[3];
    const float invn = 1.f / 131072.f;
    float mean = s1 * invn;
    float var  = s2 * invn - mean * mean;
    float inv  = rsqrtf(var + 1e-5f);
    float sc = gamma[c] * inv;
    stats[c]       = sc;
    stats[128 + c] = beta[c] - mean * sc;
  }
}

// ---------------- BN apply: bf16 y -> fp32 out -------------------------------
__global__ __launch_bounds__(256) void bn_apply(const unsigned short* __restrict__ y,
                                                const float* __restrict__ stats,
                                                float* __restrict__ out) {
  int gid = blockIdx.x * 256 + threadIdx.x;
  int base = gid << 3;
  int c = (base >> 14) & 127;
  float sc = stats[c], sh = stats[128 + c];
  uint4 u = *(const uint4*)(y + base);
  const unsigned short* us = (const unsigned short*)&u;
  float4 o0, o1;
  o0.x = bf2f(us[0]) * sc + sh;  o0.y = bf2f(us[1]) * sc + sh;
  o0.z = bf2f(us[2]) * sc + sh;  o0.w = bf2f(us[3]) * sc + sh;
  o1.x = bf2f(us[4]) * sc + sh;  o1.y = bf2f(us[5]) * sc + sh;
  o1.z = bf2f(us[6]) * sc + sh;  o1.w = bf2f(us[7]) * sc + sh;
  ((float4*)out)[gid * 2]     = o0;
  ((float4*)out)[gid * 2 + 1] = o1;
}

// ---------------- launch -----------------------------------------------------
extern "C" void kernel_launch(void* const* d_in, const int* in_sizes, int n_in,
                              void* d_out, int out_size, void* d_ws, size_t ws_size,
                              hipStream_t stream) {
  const float* x      = (const float*)d_in[0];
  const float* w_off  = (const float*)d_in[1];
  const float* w_conv = (const float*)d_in[2];
  const float* b_conv = (const float*)d_in[3];
  const float* gamma  = (const float*)d_in[4];
  const float* beta   = (const float*)d_in[5];
  float* out = (float*)d_out;

  char* ws = (char*)d_ws;
  unsigned short* x_t    = (unsigned short*)ws;            // 32M; dead after conv_off
  unsigned short* xoff_t = (unsigned short*)ws;            // aliases x_t
  unsigned short* offs = (unsigned short*)(ws + 33554432); // 64M
  unsigned short* yws  = (unsigned short*)(ws + 33554432); // aliases offs lo half
  float* ps    = (float*)(ws + 67108864);
  float* stats = (float*)(ws + 68157440);
  unsigned short* pack_off  = (unsigned short*)(ws + 100663296);  // 640 KB
  unsigned short* pack_main = (unsigned short*)(ws + 101318656);  // 320 KB
  char* zb = ws + 101646336;                               // 4 KB zeros

  prep<<<6016, 256, 0, stream>>>(x, x_t, w_off, w_conv, pack_off, pack_main,
                                 (uint4*)zb);
  conv_gemm<0, 16><<<1024, 512, 0, stream>>>(x_t, pack_off, nullptr, zb, offs, nullptr);
  deform_t<<<dim3(256, 8), 256, 0, stream>>>(x, offs, xoff_t);
  conv_gemm<1, 8><<<512, 512, 0, stream>>>(xoff_t, pack_main, b_conv, zb, yws, ps);
  bn_finalize<<<128, 256, 0, stream>>>(ps, gamma, beta, stats);
  bn_apply<<<8192, 256, 0, stream>>>(yws, stats, out);
}

// Round 8
// 304.927 us; speedup vs baseline: 1.0249x; 1.0249x over previous
//
#include <hip/hip_runtime.h>

#define B_   8
#define C_   128
#define H_   128
#define W_   128
#define HW_  16384

typedef short v8s __attribute__((ext_vector_type(8)));
typedef float v4f __attribute__((ext_vector_type(4)));

// LDS B-tile row: 130 px-slots x 32B (16ch bf16). Row stride 4160 B.
#define ROWB 4160

__device__ __forceinline__ float bf2f(unsigned short u) {
  unsigned int v = ((unsigned int)u) << 16;
  float f; __builtin_memcpy(&f, &v, 4); return f;
}
__device__ __forceinline__ unsigned short f2us(float f) {
  unsigned int u; __builtin_memcpy(&u, &f, 4);
  u += 0x7fffu + ((u >> 16) & 1u);           // RNE
  return (unsigned short)(u >> 16);
}

// ---- prep: transpose_x + both weight packs + zero scratch, one launch -------
// blocks [0,4096): transpose x fp32 [b][c][i][j] -> bf16 [b][cg][i][j][16c]
// blocks [4096,5376): pack w_off (G=16); [5376,6016): pack w_conv (G=8)
__global__ __launch_bounds__(256) void prep(const float* __restrict__ x,
                                            unsigned short* __restrict__ xt,
                                            const float* __restrict__ w_off,
                                            const float* __restrict__ w_conv,
                                            unsigned short* __restrict__ pack_off,
                                            unsigned short* __restrict__ pack_main,
                                            uint4* __restrict__ zb) {
  __shared__ alignas(16) unsigned short t[32 * 132];
  const int bid = blockIdx.x, tid = threadIdx.x;
  if (bid < 4096) {
    const int j0 = (bid & 3) * 32, i = (bid >> 2) & 127, b = bid >> 9;
    for (int e = tid; e < 1024; e += 256) {        // float4: 16B/lane, coalesced
      int c = e >> 3, j4 = (e & 7) << 2;
      float4 v = *(const float4*)&x[((b * C_ + c) * H_ + i) * W_ + j0 + j4];
      t[(j4 + 0) * 132 + c] = f2us(v.x);
      t[(j4 + 1) * 132 + c] = f2us(v.y);
      t[(j4 + 2) * 132 + c] = f2us(v.z);
      t[(j4 + 3) * 132 + c] = f2us(v.w);
    }
    __syncthreads();
    for (int f = tid; f < 1024; f += 256) {        // coalesced: 4 thr = 32B of one px
      int cg = f >> 7, g = f & 127;
      int j = g >> 2, c4 = (g & 3) << 2;
      uint2 v = *(const uint2*)&t[j * 132 + cg * 16 + c4];
      *(uint2*)(xt + ((size_t)(b * 8 + cg) * HW_ + i * W_ + j0 + j) * 16 + c4) = v;
    }
    return;
  }
  const int pb = bid - 4096;
  if (pb == 0) zb[tid] = (uint4){0u, 0u, 0u, 0u};  // 4 KB zeros
  const float* w;
  unsigned short* pack;
  int G, idx;
  if (pb < 1280) { w = w_off;  pack = pack_off;  G = 16; idx = pb * 256 + tid; }
  else           { w = w_conv; pack = pack_main; G = 8;  idx = (pb - 1280) * 256 + tid; }
  if (idx >= 20480 * G) return;
  int j  = idx & 7;
  int l  = (idx >> 3) & 63;
  int g  = (idx >> 9) % G;
  int t2 = idx / (512 * G);
  int pp = t2 % 5;
  int cc = t2 / 5;
  int oc = g * 16 + (l & 15);
  int kk = ((l >> 4) << 3) + j;
  int ic = (cc << 4) + (kk & 15);
  int rs = pp * 2 + (kk >> 4);
  float v = (rs < 9) ? w[(oc * C_ + ic) * 9 + rs] : 0.f;
  pack[idx] = f2us(v);
}

// ---------------- implicit-GEMM conv via MFMA, global_load_lds staging -------
// 8-wave / 2-output-row geometry with the PROVEN R3 inner loop. 64 VGPR +
// 64 AGPR = 128 -> launch_bounds(512,4): 2 blocks/CU = 16 waves/CU.
// Per cc: barrier -> 16x1KB DMA (4 halo rows) -> barrier -> 5 pp MFMA phases.
// MODE 0: plain bf16 store (offset conv). MODE 1: +bias+relu+BN partials.
template <int MODE, int G>
__global__ __launch_bounds__(512, 4) void conv_gemm(const unsigned short* __restrict__ xt,
                                                    const unsigned short* __restrict__ pack,
                                                    const float* __restrict__ bias,
                                                    const char* __restrict__ zb,
                                                    unsigned short* __restrict__ outp,
                                                    float* __restrict__ ps) {
  __shared__ alignas(16) char rawb[4 * ROWB];      // 16640 B
  __shared__ float bs1[128], bs2[128];

  const int nb = blockIdx.x;
  int b, ip, mt;
  {
    int xcd = nb & 7, r = nb >> 3;
    if (MODE == 0) { b = r >> 4; mt = (r >> 3) & 1; ip = xcd * 8 + (r & 7); }
    else           { b = r >> 3; mt = 0;            ip = xcd * 8 + (r & 7); }
  }
  const int i0 = ip * 2;                           // output rows i0, i0+1
  const int tid  = threadIdx.x;
  const int lane = tid & 63, wid = tid >> 6;       // wid 0..7
  const int q = lane >> 4, n = lane & 15;
  const int wr = wid & 1, wm = (wid >> 1) & 1, wn = wid >> 2;  // wn 0..1

  if (MODE == 1 && tid < 128) { bs1[tid] = 0.f; bs2[tid] = 0.f; }
  // halo-edge slots (px -1 / 128) of the 4 staged rows are always zero
  if (tid < 16) {
    int r = tid >> 2, rem = tid & 3, side = rem >> 1, h = rem & 1;
    *(uint4*)(rawb + r * ROWB + (side ? 129 * 32 : 0) + h * 16) = (uint4){0u,0u,0u,0u};
  }

  // per-pp LDS base: rs -> (staged row wr+dr, col s), 32B px stride,
  // (q&1) picks 16B half
  int boff[5];
#pragma unroll
  for (int pp = 0; pp < 5; ++pp) {
    int rs = pp * 2 + (q >> 1);
    if (rs > 8) rs = 8;                            // pad half: A is zero there
    int dr = (rs >= 6) ? 2 : ((rs >= 3) ? 1 : 0);
    int s = rs - dr * 3;
    boff[pp] = (wr + dr) * ROWB + s * 32 + (q & 1) * 16;
  }
  const int pcol = (wn * 64 + n) * 32;

  v4f acc[4][4];
#pragma unroll
  for (int a = 0; a < 4; ++a)
#pragma unroll
    for (int c = 0; c < 4; ++c) acc[a][c] = (v4f){0.f, 0.f, 0.f, 0.f};

  const v8s* packv = (const v8s*)pack;
  const int gbase = mt * 8 + wm * 4;

  for (int cc = 0; cc < 8; ++cc) {
    __syncthreads();                               // prev compute done
    // stage 4 halo rows (16 x 1KB chunks; wave w -> chunks 2w, 2w+1)
    const char* ccbase = (const char*)xt + (size_t)(b * 8 + cc) * (HW_ * 32);
#pragma unroll
    for (int t = 0; t < 2; ++t) {
      int c = wid * 2 + t, r = c >> 2, k = c & 3;
      int ii = i0 + r - 1;
      const char* src = ((unsigned)ii < 128u)
                          ? ccbase + ii * 4096 + k * 1024 + lane * 16
                          : zb + lane * 16;
      __builtin_amdgcn_global_load_lds(
          (const __attribute__((address_space(1))) unsigned int*)src,
          (__attribute__((address_space(3))) unsigned int*)(rawb + r * ROWB + 32 + k * 1024),
          16, 0, 0);
    }
    __syncthreads();                               // vmcnt drain: DMA visible

#pragma unroll
    for (int pp = 0; pp < 5; ++pp) {
      const v8s* ap = packv + ((cc * 5 + pp) * G + gbase) * 64 + lane;
      v8s Af[4];
#pragma unroll
      for (int fm = 0; fm < 4; ++fm) Af[fm] = ap[fm * 64];
      v8s Bf[4];
#pragma unroll
      for (int fn = 0; fn < 4; ++fn)
        Bf[fn] = *(const v8s*)(rawb + boff[pp] + pcol + fn * 512);
#pragma unroll
      for (int fm = 0; fm < 4; ++fm) {
#pragma unroll
        for (int fn = 0; fn < 4; ++fn)
          acc[fm][fn] = __builtin_amdgcn_mfma_f32_16x16x32_bf16(Af[fm], Bf[fn],
                                                                acc[fm][fn], 0, 0, 0);
      }
    }
  }

  const int OC = G * 16;
  const int ob = (b * OC + mt * 128 + wm * 64) * HW_ + (i0 + wr) * W_ + wn * 64;

  if (MODE == 0) {
#pragma unroll
    for (int fm = 0; fm < 4; ++fm)
#pragma unroll
      for (int fn = 0; fn < 4; ++fn)
#pragma unroll
        for (int rr = 0; rr < 4; ++rr)
          outp[ob + (fm * 16 + q * 4 + rr) * HW_ + fn * 16 + n] = f2us(acc[fm][fn][rr]);
  } else {
    float bv[4][4], s1a[4][4], s2a[4][4];
#pragma unroll
    for (int fm = 0; fm < 4; ++fm)
#pragma unroll
      for (int rr = 0; rr < 4; ++rr) {
        bv[fm][rr] = bias[wm * 64 + fm * 16 + q * 4 + rr];
        s1a[fm][rr] = 0.f; s2a[fm][rr] = 0.f;
      }
#pragma unroll
    for (int fm = 0; fm < 4; ++fm)
#pragma unroll
      for (int fn = 0; fn < 4; ++fn)
#pragma unroll
        for (int rr = 0; rr < 4; ++rr) {
          float v = acc[fm][fn][rr] + bv[fm][rr];
          v = fmaxf(v, 0.f);
          outp[ob + (fm * 16 + q * 4 + rr) * HW_ + fn * 16 + n] = f2us(v);
          s1a[fm][rr] += v; s2a[fm][rr] += v * v;
        }
#pragma unroll
    for (int fm = 0; fm < 4; ++fm)
#pragma unroll
      for (int rr = 0; rr < 4; ++rr) {
        float s1 = s1a[fm][rr], s2 = s2a[fm][rr];
#pragma unroll
        for (int m = 1; m < 16; m <<= 1) {
          s1 += __shfl_xor(s1, m);
          s2 += __shfl_xor(s2, m);
        }
        if (n == 0) {
          atomicAdd(&bs1[wm * 64 + fm * 16 + q * 4 + rr], s1);
          atomicAdd(&bs2[wm * 64 + fm * 16 + q * 4 + rr], s2);
        }
      }
    __syncthreads();
    if (tid < 128) {
      ps[nb * 128 + tid]          = bs1[tid];
      ps[131072 + nb * 128 + tid] = bs2[tid];
    }
  }
}

// ------- deform + fused transpose to [b][cg][i][j][16c] ----------------------
// Register-direct form: thread owns (b, cg, pixel), computes all 16 channels.
// Per c-iter: offs read is 4B/lane coalesced (lanes = consecutive pixels);
// gathers are near-coalesced (offsets ~N(0,0.01) => sub-pixel displacements);
// output is one dense 32B store. No LDS, no __syncthreads, 16 independent
// bilinear chains per thread (deep ILP).
__global__ __launch_bounds__(256) void deform_t(const float* __restrict__ x,
                                                const unsigned short* __restrict__ offs,
                                                unsigned short* __restrict__ xofft) {
  const int gid = blockIdx.x * 256 + threadIdx.x;  // ((b*8+cg)<<14) | pix
  const int pix = gid & (HW_ - 1);
  const int bcg = gid >> 14;                       // 0..63
  const int b = bcg >> 3, cg = bcg & 7;
  const int i = pix >> 7, j = pix & 127;
  const float fi = (float)i, fj = (float)j;
  const float* xb = x + (((size_t)b * C_) << 14);
  const unsigned short* ob = offs + ((size_t)b << 22) + 2 * (size_t)pix;
  unsigned int packed[8];
#pragma unroll
  for (int u = 0; u < 16; ++u) {
    const int c = cg * 16 + u;
    unsigned int pr = *(const unsigned int*)(ob + ((size_t)c << 15));  // quirky reshape
    float oy = bf2f((unsigned short)(pr & 0xffffu));
    float ox = bf2f((unsigned short)(pr >> 16));
    float yc = fminf(fmaxf(oy + fi, 0.f), 127.f);
    float xc = fminf(fmaxf(ox + fj, 0.f), 127.f);
    float y0f = floorf(yc), y1f = ceilf(yc);
    float x0f = floorf(xc), x1f = ceilf(xc);
    int y0 = (int)y0f, y1 = (int)y1f, x0 = (int)x0f, x1 = (int)x1f;
    const float* img = xb + (c << 14);
    float v_lt = img[y0 * W_ + x0];
    float v_rb = img[y1 * W_ + x1];
    float v_lb = img[y0 * W_ + x1];
    float v_rt = img[y1 * W_ + x0];
    float dy = yc - y0f, dx = xc - x0f;
    float v_t = v_lt + (v_rt - v_lt) * dy;
    float v_b = v_lb + (v_rb - v_lb) * dy;
    float o   = v_t + (v_b - v_t) * dx;
    unsigned int us = (unsigned int)f2us(o);
    if (u & 1) packed[u >> 1] |= us << 16;
    else       packed[u >> 1]  = us;
  }
  uint4* dst = (uint4*)(xofft + ((size_t)gid << 4));
  dst[0] = (uint4){packed[0], packed[1], packed[2], packed[3]};
  dst[1] = (uint4){packed[4], packed[5], packed[6], packed[7]};
}

// ---------------- BN finalize: fold stats into scale/shift -------------------
__global__ __launch_bounds__(256) void bn_finalize(const float* __restrict__ ps,
                                                   const float* __restrict__ gamma,
                                                   const float* __restrict__ beta,
                                                   float* __restrict__ stats) {
  const int c = blockIdx.x, tid = threadIdx.x;
  float s1 = 0.f, s2 = 0.f;
  for (int k = tid; k < 512; k += 256) {
    s1 += ps[k * 128 + c];
    s2 += ps[131072 + k * 128 + c];
  }
#pragma unroll
  for (int m = 32; m > 0; m >>= 1) {
    s1 += __shfl_down(s1, m);
    s2 += __shfl_down(s2, m);
  }
  __shared__ float l1[4], l2[4];
  int wid = tid >> 6;
  if ((tid & 63) == 0) { l1[wid] = s1; l2[wid] = s2; }
  __syncthreads();
  if (tid == 0) {
    s1 = l1[0] + l1[1] + l1[2] + l1[3];
    s2 = l2[0] + l2[1] + l2[2] + l2[3];
    const float invn = 1.f / 131072.f;
    float mean = s1 * invn;
    float var  = s2 * invn - mean * mean;
    float inv  = rsqrtf(var + 1e-5f);
    float sc = gamma[c] * inv;
    stats[c]       = sc;
    stats[128 + c] = beta[c] - mean * sc;
  }
}

// ---------------- BN apply: bf16 y -> fp32 out, 16 elems/thread --------------
__global__ __launch_bounds__(256) void bn_apply(const unsigned short* __restrict__ y,
                                                const float* __restrict__ stats,
                                                float* __restrict__ out) {
  int gid = blockIdx.x * 256 + threadIdx.x;
  int base = gid << 4;                             // 16 bf16, same channel
  int c = (base >> 14) & 127;
  float sc = stats[c], sh = stats[128 + c];
  uint4 u0 = ((const uint4*)y)[gid * 2];
  uint4 u1 = ((const uint4*)y)[gid * 2 + 1];
  const unsigned short* us0 = (const unsigned short*)&u0;
  const unsigned short* us1 = (const unsigned short*)&u1;
  float4 o[4];
#pragma unroll
  for (int k = 0; k < 4; ++k) {
    const unsigned short* s = (k < 2) ? us0 + k * 4 : us1 + (k - 2) * 4;
    o[k].x = bf2f(s[0]) * sc + sh;
    o[k].y = bf2f(s[1]) * sc + sh;
    o[k].z = bf2f(s[2]) * sc + sh;
    o[k].w = bf2f(s[3]) * sc + sh;
  }
#pragma unroll
  for (int k = 0; k < 4; ++k) ((float4*)out)[gid * 4 + k] = o[k];
}

// ---------------- launch -----------------------------------------------------
extern "C" void kernel_launch(void* const* d_in, const int* in_sizes, int n_in,
                              void* d_out, int out_size, void* d_ws, size_t ws_size,
                              hipStream_t stream) {
  const float* x      = (const float*)d_in[0];
  const float* w_off  = (const float*)d_in[1];
  const float* w_conv = (const float*)d_in[2];
  const float* b_conv = (const float*)d_in[3];
  const float* gamma  = (const float*)d_in[4];
  const float* beta   = (const float*)d_in[5];
  float* out = (float*)d_out;

  char* ws = (char*)d_ws;
  unsigned short* x_t    = (unsigned short*)ws;            // 32M; dead after conv_off
  unsigned short* xoff_t = (unsigned short*)ws;            // aliases x_t
  unsigned short* offs = (unsigned short*)(ws + 33554432); // 64M
  unsigned short* yws  = (unsigned short*)(ws + 33554432); // aliases offs lo half
  float* ps    = (float*)(ws + 67108864);
  float* stats = (float*)(ws + 68157440);
  unsigned short* pack_off  = (unsigned short*)(ws + 100663296);  // 640 KB
  unsigned short* pack_main = (unsigned short*)(ws + 101318656);  // 320 KB
  char* zb = ws + 101646336;                               // 4 KB zeros

  prep<<<6016, 256, 0, stream>>>(x, x_t, w_off, w_conv, pack_off, pack_main,
                                 (uint4*)zb);
  conv_gemm<0, 16><<<1024, 512, 0, stream>>>(x_t, pack_off, nullptr, zb, offs, nullptr);
  deform_t<<<4096, 256, 0, stream>>>(x, offs, xoff_t);
  conv_gemm<1, 8><<<512, 512, 0, stream>>>(xoff_t, pack_main, b_conv, zb, yws, ps);
  bn_finalize<<<128, 256, 0, stream>>>(ps, gamma, beta, stats);
  bn_apply<<<4096, 256, 0, stream>>>(yws, stats, out);
}